// Round 4
// baseline (181.779 us; speedup 1.0000x reference)
//
#include <hip/hip_runtime.h>

// STDP delta_w on MI355X, bf16-MFMA formulation (2-dispatch).
//   term1: dW1[o,p] = sum_k O[k,o]*TP[k,p], K = T*B = 1024  -> bf16 MFMA GEMM
//   term2: -coef[o]*W[o,p], coef[o] = sum_k O[k,o]*PO[k,o]  -> fp32 epilogue
//
// R10: converter rewritten for latency hiding (GEMM = verbatim R9, passed):
//   512 blocks x 256 thr (8 waves/CU vs old 4), p-chunk 16, 1 chain/thread.
//   Register double-buffer: chunk c+1's 8 scalar loads issued before chunk c's
//   recurrence (T14); raw s_barrier + lgkmcnt(0) only -> prefetch loads are
//   never drained by a barrier (the old __syncthreads vmcnt(0) drain killed
//   overlap). LDS only for the k-transpose: ot[k 128][p 16 +1 pad] u16
//   (2-way banks = free), flush = u16 gather + ushort8 contiguous stores
//   (same pattern family as verified R4). Math identical to R4 branch.
//
// ws: AT bf16 [4096][1024] (8MB) | BT bf16 [4096][1024] (8MB) | coef f32[4096]

#define T_STEPS 64
#define B_SZ    16
#define PRE     4096
#define POST    4096
#define K_TOT   1024

typedef __attribute__((ext_vector_type(8))) unsigned short ushort8;
typedef __attribute__((ext_vector_type(8))) __bf16 bf16x8;
typedef __attribute__((ext_vector_type(4))) float floatx4;

__device__ __forceinline__ unsigned short f2bf(float f) {
    unsigned int u = __float_as_uint(f);
    u += 0x7fff + ((u >> 16) & 1);          // round-to-nearest-even
    return (unsigned short)(u >> 16);
}

__device__ __forceinline__ void glds16(const void* g, void* l) {
    __builtin_amdgcn_global_load_lds((const __attribute__((address_space(1))) void*)g,
                                     (__attribute__((address_space(3))) void*)l,
                                     16, 0, 0);
}

// ---------------------------------------------------------------------------
// Converter R10: grid = 512 blocks (matrix = blk>>8, p-chunk16 = blk&255),
// 256 thr; thread owns chain (b = tid>>4, p = tid&15) for all 64 t.
__global__ __launch_bounds__(256) void trace_convert(
        const float* __restrict__ in_spikes,
        const float* __restrict__ out_spikes,
        unsigned short* __restrict__ AT,
        unsigned short* __restrict__ BT,
        float* __restrict__ coef) {
    __shared__ unsigned short ot[128 * 17];  // [128 k][16 p + 1 pad], 4.25 KB
    __shared__ float cbuf[16 * 17];
    const int tid  = threadIdx.x;
    const bool isA = blockIdx.x >= 256;
    const int p0 = (blockIdx.x & 255) * 16;
    const float* src = isA ? out_spikes : in_spikes;
    unsigned short* dst = isA ? AT : BT;

    const int p = tid & 15;
    const int b = tid >> 4;
    // element (t): gbase[t * 65536]
    const float* gbase = src + (size_t)b * PRE + p0 + p;

    const int pf = tid >> 4;                 // flush: p-row 0..15
    const int ch = tid & 15;                 // flush: 16-B chunk (8 k) 0..15
    unsigned short* dstf = &dst[(size_t)(p0 + pf) * K_TOT + ch * 8];

    float x[2][8];
    float st = 0.f, c0 = 0.f;

    // prologue: chunk 0 loads
    #pragma unroll
    for (int tl = 0; tl < 8; ++tl) x[0][tl] = gbase[(size_t)tl * 65536];

    #pragma unroll
    for (int c = 0; c < 8; ++c) {
        // prefetch chunk c+1 (stays in flight across the raw barriers below)
        if (c < 7) {
            #pragma unroll
            for (int tl = 0; tl < 8; ++tl)
                x[(c + 1) & 1][tl] = gbase[(size_t)((c + 1) * 8 + tl) * 65536];
        }
        // recurrence: 8 t-steps, 1 chain
        #pragma unroll
        for (int tl = 0; tl < 8; ++tl) {
            const float xv = x[c & 1][tl];
            unsigned short ov;
            if (isA) {
                st = 0.5f * st + xv;         // po update
                c0 += xv * st;               // o * po
                ov = f2bf(xv);               // A stores raw o
            } else {
                st = fminf(fmaxf(0.5f * st + xv, 0.f), 1.f);
                ov = f2bf(st);               // B stores clipped trace
            }
            ot[(tl * 16 + b) * 17 + p] = ov;
        }
        asm volatile("s_waitcnt lgkmcnt(0)" ::: "memory");
        __builtin_amdgcn_s_barrier();
        __builtin_amdgcn_sched_barrier(0);

        // flush: 16 p-rows x 128 k, one ushort8 per thread, contiguous rows
        ushort8 v;
        #pragma unroll
        for (int s = 0; s < 8; ++s) v[s] = ot[(ch * 8 + s) * 17 + pf];
        *(ushort8*)&dstf[c * 128] = v;

        asm volatile("s_waitcnt lgkmcnt(0)" ::: "memory");
        __builtin_amdgcn_s_barrier();
        __builtin_amdgcn_sched_barrier(0);
    }

    if (isA) {
        cbuf[b * 17 + p] = c0;
        asm volatile("s_waitcnt lgkmcnt(0)" ::: "memory");
        __builtin_amdgcn_s_barrier();
        if (tid < 16) {
            float s = 0.f;
            #pragma unroll
            for (int r = 0; r < 16; ++r) s += cbuf[r * 17 + tid];
            coef[p0 + tid] = s;
        }
    }
}

// ---------------------------------------------------------------------------
// 8-phase GEMM — verbatim R9 (passed; 67.5 us, kept unchanged this round).
#define NTILES 16
#define LOFF(buf, isB, kh) ((buf) * 65536 + (isB) * 32768 + (kh) * 16384)

__global__ __launch_bounds__(512, 2) void stdp_gemm_mfma(
        const unsigned short* __restrict__ AT,   // [POST][K] bf16 bits
        const unsigned short* __restrict__ BT,   // [PRE][K]  bf16 bits
        const float* __restrict__ W,             // [POST][PRE]
        const float* __restrict__ coef,          // [POST]
        float* __restrict__ Cout) {              // [POST][PRE]
    __shared__ __align__(16) char ldsraw[131072];   // 128 KB -> 1 block/CU

    const int tid  = threadIdx.x;
    const int lane = tid & 63;
    const int wave = tid >> 6;

    // XCD-bijective swizzle: 256 blocks = 8 XCD x 32; each XCD: 2 m-panels x 16 n.
    const int bid = blockIdx.x;
    const int f   = (bid & 7) * 32 + (bid >> 3);
    const int m0  = (f >> 4) * 256;
    const int n0  = (f & 15) * 256;

    const int wm  = (wave >> 2) * 128;           // 2 M-groups (rows within tile)
    const int wn  = (wave & 3) * 64;             // 4 N-groups
    const int rml = lane & 15;                   // fragment row within 16
    const int q   = lane >> 4;                   // k-chunk 0..3 within 32-k half
    const int swz16 = ((q ^ ((rml >> 1) & 3)) << 4);  // swizzled chunk byte offset

    floatx4 acc[8][4];
    #pragma unroll
    for (int i = 0; i < 8; ++i)
        #pragma unroll
        for (int j = 0; j < 4; ++j)
            acc[i][j] = (floatx4){0.f, 0.f, 0.f, 0.f};
    bf16x8 bv[4];                                // B-frags, live across phase pairs

    const int cid0 = wave * 64 + lane;
    const int row0 = cid0 >> 2;
    const int g0   = (cid0 & 3) ^ ((row0 >> 1) & 3);
    const unsigned short* gA0 = AT + (size_t)(m0 + row0) * K_TOT + g0 * 8;
    const unsigned short* gB0 = BT + (size_t)(n0 + row0) * K_TOT + g0 * 8;

    #define STG(isB, t, kh)                                                        \
        do {                                                                       \
            const unsigned short* s0_ = ((isB) ? gB0 : gA0) + (t) * 64 + (kh) * 32;\
            char* d_ = ldsraw + LOFF((t) & 1, (isB), (kh)) + wave * 1024;          \
            glds16(s0_, d_);                                                       \
            glds16(s0_ + (size_t)128 * K_TOT, d_ + 8192);                          \
        } while (0)

    #define PHASE(bufc, khc, mqc, SISB, ST, SKH, SCOND, WM)                        \
        do {                                                                       \
            const char* Ab_ = ldsraw + LOFF(bufc, 0, khc);                         \
            const char* Bb_ = ldsraw + LOFF(bufc, 1, khc);                         \
            if ((mqc) == 0) {                                                      \
                _Pragma("unroll")                                                  \
                for (int ni = 0; ni < 4; ++ni)                                     \
                    bv[ni] = *(const bf16x8*)(Bb_ + (wn + ni * 16 + rml) * 64 + swz16); \
            }                                                                      \
            bf16x8 af_[4];                                                         \
            _Pragma("unroll")                                                      \
            for (int k4 = 0; k4 < 4; ++k4)                                         \
                af_[k4] = *(const bf16x8*)(Ab_ + (wm + (mqc) * 64 + k4 * 16 + rml) * 64 + swz16); \
            if (SCOND) STG(SISB, ST, SKH);                                         \
            if ((WM) == 1)      asm volatile("s_waitcnt vmcnt(4)" ::: "memory");   \
            else if ((WM) == 2) asm volatile("s_waitcnt vmcnt(0)" ::: "memory");   \
            __builtin_amdgcn_s_barrier();                                          \
            __builtin_amdgcn_sched_barrier(0);                                     \
            __builtin_amdgcn_s_setprio(1);                                         \
            _Pragma("unroll")                                                      \
            for (int k4 = 0; k4 < 4; ++k4)                                         \
                _Pragma("unroll")                                                  \
                for (int ni = 0; ni < 4; ++ni)                                     \
                    acc[(mqc) * 4 + k4][ni] = __builtin_amdgcn_mfma_f32_16x16x32_bf16( \
                        af_[k4], bv[ni], acc[(mqc) * 4 + k4][ni], 0, 0, 0);        \
            __builtin_amdgcn_s_setprio(0);                                         \
            __builtin_amdgcn_s_barrier();                                          \
            __builtin_amdgcn_sched_barrier(0);                                     \
        } while (0)

    STG(0, 0, 0); STG(1, 0, 0); STG(0, 0, 1); STG(1, 0, 1);
    STG(0, 1, 0); STG(1, 1, 0); STG(0, 1, 1); STG(1, 1, 1);
    asm volatile("s_waitcnt vmcnt(8)" ::: "memory");
    __builtin_amdgcn_s_barrier();
    __builtin_amdgcn_sched_barrier(0);

    for (int i = 0; i < 8; ++i) {
        const int t2 = 2 * i + 2, t3 = 2 * i + 3, tA = 2 * i + 1;
        const int wm4 = (i < 7) ? 1 : 2;         // ph4 wait: publish buf1
        const int wm8 = (i < 7) ? 1 : 0;         // ph8 wait: publish buf0 (none at end)
        PHASE(0, 0, 0, 0, tA, 1, i > 0,      0);     // ph1
        PHASE(0, 0, 1, 1, tA, 1, i > 0,      0);     // ph2
        PHASE(0, 1, 0, 0, t2, 0, t2 < NTILES, 0);    // ph3
        PHASE(0, 1, 1, 1, t2, 0, t2 < NTILES, wm4);  // ph4
        PHASE(1, 0, 0, 0, t2, 1, t2 < NTILES, 0);    // ph5
        PHASE(1, 0, 1, 1, t2, 1, t2 < NTILES, 0);    // ph6
        PHASE(1, 1, 0, 0, t3, 0, t3 < NTILES, 0);    // ph7
        PHASE(1, 1, 1, 1, t3, 0, t3 < NTILES, wm8);  // ph8
    }

    // Epilogue: C = acc - coef[o]*W. C/D layout: col=lane&15, row=quad*4+reg.
    const int colp = n0 + wn + rml;
    const int q4   = lane >> 4;
    #pragma unroll
    for (int mi = 0; mi < 8; ++mi) {
        #pragma unroll
        for (int r = 0; r < 4; ++r) {
            const int o = m0 + wm + mi * 16 + q4 * 4 + r;
            const float cf = coef[o];
            const float* wrow = &W[(size_t)o * PRE + colp];
            float* crow = &Cout[(size_t)o * PRE + colp];
            #pragma unroll
            for (int ni = 0; ni < 4; ++ni)
                crow[ni * 16] = acc[mi][ni][r] - cf * wrow[ni * 16];
        }
    }
    #undef PHASE
    #undef STG
}

// ---------------------------------------------------------------------------
extern "C" void kernel_launch(void* const* d_in, const int* in_sizes, int n_in,
                              void* d_out, int out_size, void* d_ws, size_t ws_size,
                              hipStream_t stream) {
    const float* in_spikes  = (const float*)d_in[0];
    const float* out_spikes = (const float*)d_in[1];
    const float* weight     = (const float*)d_in[2];
    float* out = (float*)d_out;

    unsigned short* AT = (unsigned short*)d_ws;                 // 8 MB
    unsigned short* BT = AT + (size_t)POST * K_TOT;             // 8 MB
    float* coef = (float*)(BT + (size_t)PRE * K_TOT);           // 16 KB

    trace_convert<<<512, 256, 0, stream>>>(in_spikes, out_spikes, AT, BT, coef);

    dim3 grid(256);
    stdp_gemm_mfma<<<grid, 512, 0, stream>>>(AT, BT, weight, coef, out);
}